// Round 14
// baseline (333.613 us; speedup 1.0000x reference)
//
#include <hip/hip_runtime.h>

typedef float f32x4_t __attribute__((ext_vector_type(4)));
typedef __bf16 bf16x8_t __attribute__((ext_vector_type(8)));
typedef unsigned short u16x8_t __attribute__((ext_vector_type(8)));

// ---- geometry ----
#define NPIX        100352      // 32*56*56
#define PIX_PER_IMG 3136        // 56*56
#define PH          58
#define PPIX        3364        // 58*58
#define C_IN        128
#define C_OUT       256
#define NV4         3211264     // x as float4 count
#define NWELEM      294912      // 3*3*128*256
#define MT128       784         // NPIX/128
#define NPADPIX     107648      // 32*58*58

// ---- ws byte offsets ----
#define OFF_ENC     0           // 4 x u32 (x min/max, wfold min/max encodings)
#define OFF_SCALE   64          // 256 f32
#define OFF_BIAS    1152        // 256 f32
#define OFF_WT      4096        // 589824 B bf16 [9][256 f][128 c]
#define OFF_WQT     593920      // 589824 B
#define OFF_PSUM    1183744     // 1568*128 f32 = 802816 B
#define OFF_WFMIN   1988608     // 256 f32
#define OFF_WFMAX   1989632     // 256 f32
#define OFF_PSQ     1990656     // 1568*128 f32
#define OFF_XPAD    2793472     // 27557888 B bf16 [32][58][58][128]
#define OFF_XQPAD   30351360    // 27557888 B   (end: 57909248)

// ---- helpers ----
__device__ __forceinline__ unsigned short f2bf(float x) {
  unsigned u = __float_as_uint(x);
  u += 0x7FFFu + ((u >> 16) & 1u);   // RNE
  return (unsigned short)(u >> 16);
}
__device__ __forceinline__ unsigned encf(float v) {
  unsigned u = __float_as_uint(v);
  return (u & 0x80000000u) ? ~u : (u | 0x80000000u);
}
__device__ __forceinline__ float decf(unsigned e) {
  unsigned u = (e & 0x80000000u) ? (e ^ 0x80000000u) : ~e;
  return __uint_as_float(u);
}
__device__ __forceinline__ void gl_lds16(const void* g, void* l) {
  auto gp = (const __attribute__((address_space(1))) unsigned*)(const unsigned*)g;
  auto lp = (__attribute__((address_space(3))) unsigned*)(unsigned*)l;
  __builtin_amdgcn_global_load_lds(gp, lp, 16, 0, 0);
}
#define SCHED_FENCE() __builtin_amdgcn_sched_barrier(0)

// ---- kernels ----
__global__ void kinit(unsigned* enc) {
  enc[0] = 0xFFFFFFFFu; enc[1] = 0u;   // x min/max encodings
  enc[2] = 0xFFFFFFFFu; enc[3] = 0u;   // wfold min/max encodings
}

__global__ void kminmax(const float4* __restrict__ x, unsigned* __restrict__ enc) {
  const int tid = blockIdx.x * blockDim.x + threadIdx.x;
  const int stride = gridDim.x * blockDim.x;
  float mn = 3.4e38f, mx = -3.4e38f;
  for (int i = tid; i < NV4; i += stride) {
    float4 v = x[i];
    mn = fminf(mn, fminf(fminf(v.x, v.y), fminf(v.z, v.w)));
    mx = fmaxf(mx, fmaxf(fmaxf(v.x, v.y), fmaxf(v.z, v.w)));
  }
  #pragma unroll
  for (int off = 32; off > 0; off >>= 1) {
    mn = fminf(mn, __shfl_xor(mn, off));
    mx = fmaxf(mx, __shfl_xor(mx, off));
  }
  __shared__ float smn[4], smx[4];
  const int lane = threadIdx.x & 63, w = threadIdx.x >> 6;
  if (lane == 0) { smn[w] = mn; smx[w] = mx; }
  __syncthreads();
  if (threadIdx.x == 0) {
    mn = fminf(fminf(smn[0], smn[1]), fminf(smn[2], smn[3]));
    mx = fmaxf(fmaxf(smx[0], smx[1]), fmaxf(smx[2], smx[3]));
    atomicMin(&enc[0], encf(mn));
    atomicMax(&enc[1], encf(mx));
  }
}

// quantized folded weights: wqt [tap][256 f][128 c] bf16
__global__ void kwq(const float* __restrict__ W, const float* __restrict__ scale,
                    const unsigned* __restrict__ enc, unsigned short* __restrict__ wqt) {
  const int idx = blockIdx.x * 256 + threadIdx.x;
  if (idx >= NWELEM) return;
  const int c = idx & 127;
  const int f = (idx >> 7) & 255;
  const int tap = idx >> 15;
  const float wmn = decf(enc[2]), wmx = decf(enc[3]);
  const float wstep = (wmx - wmn) / 255.0f;
  const float wrstep = 255.0f / (wmx - wmn);
  const float v = W[(tap * 128 + c) * 256 + f] * scale[f];
  const float q = rintf((v - wmn) * wrstep) * wstep + wmn;
  wqt[idx] = f2bf(q);
}

// fused prep kernel, 3 regions:
//  [0, 6728):      pad-fill x -> xpad bf16 + xqpad bf16 (quantized), zero border
//  [6728, 7880):   W -> Wt [tap][256 f][128 c] bf16
//  [7880, 8136):   per-f min/max of W (stats-independent) -> wfmin/wfmax[256]
__global__ void kpadfill(const float* __restrict__ x, const unsigned* __restrict__ enc,
                         unsigned short* __restrict__ xpad, unsigned short* __restrict__ xqpad,
                         const float* __restrict__ W, unsigned short* __restrict__ wtt,
                         float* __restrict__ wfmin, float* __restrict__ wfmax)
{
  if (blockIdx.x >= 7880) {
    const int f = blockIdx.x - 7880;
    float mn = 3.4e38f, mx = -3.4e38f;
    for (int e = threadIdx.x; e < 1152; e += 256) {
      const float v = W[e * 256 + f];
      mn = fminf(mn, v); mx = fmaxf(mx, v);
    }
    #pragma unroll
    for (int off = 32; off > 0; off >>= 1) {
      mn = fminf(mn, __shfl_xor(mn, off));
      mx = fmaxf(mx, __shfl_xor(mx, off));
    }
    __shared__ float rmn[4], rmx[4];
    const int lane = threadIdx.x & 63, w = threadIdx.x >> 6;
    if (lane == 0) { rmn[w] = mn; rmx[w] = mx; }
    __syncthreads();
    if (threadIdx.x == 0) {
      wfmin[f] = fminf(fminf(rmn[0], rmn[1]), fminf(rmn[2], rmn[3]));
      wfmax[f] = fmaxf(fmaxf(rmx[0], rmx[1]), fmaxf(rmx[2], rmx[3]));
    }
    return;
  }
  if (blockIdx.x >= 6728) {
    const int idx = (blockIdx.x - 6728) * 256 + threadIdx.x;
    if (idx < NWELEM) {
      const int c = idx & 127;
      const int f = (idx >> 7) & 255;
      const int tap = idx >> 15;
      wtt[idx] = f2bf(W[(tap * 128 + c) * 256 + f]);
    }
    return;
  }
  const int tid = blockIdx.x * 256 + threadIdx.x;
  if (tid >= NPADPIX * 16) return;
  const int pp = tid >> 4;
  const int c8 = (tid & 15) << 3;
  const int n = pp / PPIX;
  const int rem = pp - n * PPIX;
  const int hp = rem / PH;
  const int wp = rem - hp * PH;
  u16x8_t vb, vq;
  #pragma unroll
  for (int j = 0; j < 8; ++j) { vb[j] = 0; vq[j] = 0; }
  if (hp >= 1 && hp <= 56 && wp >= 1 && wp <= 56) {
    const float mn = decf(enc[0]), mx = decf(enc[1]);
    const float step = (mx - mn) / 255.0f, rstep = 255.0f / (mx - mn);
    const float* src = x + ((n * PIX_PER_IMG) + (hp - 1) * 56 + (wp - 1)) * C_IN + c8;
    const float4 a = *(const float4*)src;
    const float4 b = *(const float4*)(src + 4);
    const float v[8] = {a.x, a.y, a.z, a.w, b.x, b.y, b.z, b.w};
    #pragma unroll
    for (int j = 0; j < 8; ++j) {
      vb[j] = f2bf(v[j]);
      const float qv = rintf((v[j] - mn) * rstep) * step + mn;
      vq[j] = f2bf(qv);
    }
  }
  *(u16x8_t*)(xpad + pp * C_IN + c8) = vb;
  *(u16x8_t*)(xqpad + pp * C_IN + c8) = vq;
}

// implicit-GEMM conv. BM=128, BN=128 (bn = N-half), BK=32. 256 threads, 4 waves
// 2(M)x2(N), wave tile 64x64, acc 4x4 f32x4 (64 AGPR). A staged in LDS (2 x 8KB
// dbuf, R11-proven packed layout + XOR swizzle, rule #21); B (weights, L2-hot)
// loaded DIRECTLY global->reg via inline-asm global_load_dwordx4, double-buffered
// by loop-unroll-2 (static reg sets, rule #20), all waits manual (vmcnt ledger:
// per iter issue [A(t+2) x2, B(t+2) x4]; top-of-iter vmcnt(6) retires A(t)+B(t)).
// LDS bytes/tile: 24KB (A only) vs 44KB R8-normalized. ~145 regs -> 3 blocks/CU.
// STATS=1: per-block column sum/sumsq partials. STATS=0: out = relu(conv + bias).
template<int STATS>
__global__ __launch_bounds__(256, 3)
void kconv(const unsigned short* __restrict__ xin,   // padded bf16 [32][58][58][128]
           const unsigned short* __restrict__ wt,    // bf16 [9][256 f][128 c]
           float* __restrict__ out,
           const float* __restrict__ bias,
           float* __restrict__ psum,
           float* __restrict__ psq)
{
  // XCD-aware bijective swizzle: 1568 = 8*196; (bm,0)/(bm,1) adjacent on same XCD.
  const int bid = blockIdx.x;
  const int slot = (bid & 7) * 196 + (bid >> 3);   // 0..1567
  const int bm = slot >> 1;                         // 0..783 (128-pixel tiles)
  const int bn = slot & 1;                          // N-half

  const int tid = threadIdx.x;
  const int lane = tid & 63;
  const int wid = tid >> 6;          // 0..3
  const int wm = wid >> 1;           // 0..1
  const int wn = wid & 1;            // 0..1
  const int l16 = lane & 15;
  const int rsub = lane >> 4;

  __shared__ __align__(16) unsigned char smem[16384];   // 2 x 8KB A buffers

  // ---- A staging offsets (global source pre-swizzled; LDS dest linear) ----
  // load j in {0,1}: row = j*32 + (tid>>3) (0..63), phys chunk = tid&7
  unsigned aoff[2];
  {
    const int pc = tid & 7;
    #pragma unroll
    for (int j = 0; j < 2; ++j) {
      const int row = j * 32 + (tid >> 3);
      const int lc = pc ^ (row & 7);
      const int pix = bm * 128 + row + 64 * (lc >> 2);
      const int n = pix / PIX_PER_IMG;
      const int rem = pix - n * PIX_PER_IMG;
      const int hh = rem / 56;
      const int ww = rem - hh * 56;
      aoff[j] = (unsigned)((n * PPIX + hh * PH + ww) * C_IN + (lc & 3) * 8);
    }
  }
  // ---- A ds_read byte offsets ----
  int a_rd[4];
  #pragma unroll
  for (int im = 0; im < 4; ++im) {
    const int p = wm * 64 + im * 16 + l16;          // pixel in tile, 0..127
    const int row = p & 63, half = p >> 6;
    const int phys = (half * 4 + rsub) ^ (row & 7);
    a_rd[im] = row * 128 + phys * 16;
  }
  // ---- B per-thread byte offsets (constant across tiles; base carries tap+cq) ----
  unsigned boffB[4];
  #pragma unroll
  for (int in = 0; in < 4; ++in) {
    const int f = bn * 128 + wn * 64 + in * 16 + l16;
    boffB[in] = (unsigned)(f * C_IN + rsub * 8) * 2u;   // bytes
  }

  f32x4_t acc[4][4];
  #pragma unroll
  for (int im = 0; im < 4; ++im)
    #pragma unroll
    for (int in = 0; in < 4; ++in)
      #pragma unroll
      for (int j = 0; j < 4; ++j) acc[im][in][j] = 0.f;

  // stage A of tile s into buffer (s&1): 2 gload_lds/thread
  auto stage = [&](int s) {
    const int tap = s >> 2;
    const int cq = (s & 3) * 32;
    const int kh = tap / 3, kw = tap - kh * 3;
    const unsigned atap = (unsigned)((kh * PH + kw) * C_IN + cq);
    unsigned char* sA = smem + (s & 1) * 8192;
    gl_lds16(xin + atap + aoff[0], sA + wid * 1024);
    gl_lds16(xin + atap + aoff[1], sA + 4096 + wid * 1024);
  };

  // load B frags of tile s into registers (inline asm; waits are manual)
  auto loadB = [&](int s, bf16x8_t (&bv)[4]) {
    const int tap = s >> 2;
    const int cq = (s & 3) * 32;
    const unsigned short* base = wt + tap * (C_OUT * C_IN) + cq;
    #pragma unroll
    for (int in = 0; in < 4; ++in)
      asm volatile("global_load_dwordx4 %0, %1, %2"
                   : "=v"(bv[in])
                   : "v"(boffB[in]), "s"(base)
                   : "memory");
  };

  auto compute = [&](int s, bf16x8_t (&bv)[4]) {
    const unsigned char* sA = smem + (s & 1) * 8192;
    bf16x8_t av[4];
    #pragma unroll
    for (int im = 0; im < 4; ++im) av[im] = *(const bf16x8_t*)(sA + a_rd[im]);
    #pragma unroll
    for (int im = 0; im < 4; ++im)
      #pragma unroll
      for (int in = 0; in < 4; ++in)
        acc[im][in] = __builtin_amdgcn_mfma_f32_16x16x32_bf16(av[im], bv[in], acc[im][in], 0, 0, 0);
  };

  bf16x8_t bvA[4], bvB[4];
  // prologue (issue order matters: A(s) before B(s))
  stage(0); loadB(0, bvA);
  stage(1); loadB(1, bvB);

  // 36 K-tiles (9 taps x 4 channel-quarters), unroll-2 for static B reg sets.
  // Ledger at top of iter s: queue = [A(s)2 B(s)4 A(s+1)2 B(s+1)4]; vmcnt(6)
  // retires A(s)+B(s). vmcnt(0) only at s=35.
  #pragma unroll 1
  for (int s = 0; s < 36; s += 2) {
    // even sub-iter (uses bvA)
    asm volatile("s_waitcnt vmcnt(6)" ::: "memory");
    SCHED_FENCE();
    __builtin_amdgcn_s_barrier();
    SCHED_FENCE();
    compute(s, bvA);
    SCHED_FENCE();
    __builtin_amdgcn_s_barrier();
    SCHED_FENCE();
    if (s + 2 < 36) { stage(s + 2); loadB(s + 2, bvA); }
    // odd sub-iter (uses bvB)
    if (s + 1 < 35) asm volatile("s_waitcnt vmcnt(6)" ::: "memory");
    else            asm volatile("s_waitcnt vmcnt(0)" ::: "memory");
    SCHED_FENCE();
    __builtin_amdgcn_s_barrier();
    SCHED_FENCE();
    compute(s + 1, bvB);
    SCHED_FENCE();
    __builtin_amdgcn_s_barrier();
    SCHED_FENCE();
    if (s + 3 < 36) { stage(s + 3); loadB(s + 3, bvB); }
  }

  if (STATS) {
    __syncthreads();
    float* sb = (float*)smem;      // [4 waves][64 cols] sums; sumsq at +256
    #pragma unroll
    for (int in = 0; in < 4; ++in) {
      float s = 0.f, q = 0.f;
      #pragma unroll
      for (int im = 0; im < 4; ++im)
        #pragma unroll
        for (int j = 0; j < 4; ++j) {
          const float v = acc[im][in][j];
          s += v; q += v * v;
        }
      s += __shfl_xor(s, 16); q += __shfl_xor(q, 16);
      s += __shfl_xor(s, 32); q += __shfl_xor(q, 32);
      if (lane < 16) {
        sb[wid * 64 + in * 16 + lane] = s;
        sb[256 + wid * 64 + in * 16 + lane] = q;
      }
    }
    __syncthreads();
    if (tid < 128) {
      const int wn2 = tid >> 6, cl = tid & 63;   // channel c = wn2*64 + cl
      const float s = sb[wn2 * 64 + cl] + sb[(2 + wn2) * 64 + cl];
      const float q = sb[256 + wn2 * 64 + cl] + sb[256 + (2 + wn2) * 64 + cl];
      psum[(bm * 2 + bn) * 128 + tid] = s;
      psq[(bm * 2 + bn) * 128 + tid] = q;
    }
  } else {
    float bval[4];
    #pragma unroll
    for (int in = 0; in < 4; ++in)
      bval[in] = bias[bn * 128 + wn * 64 + in * 16 + l16];
    #pragma unroll
    for (int im = 0; im < 4; ++im) {
      #pragma unroll
      for (int j = 0; j < 4; ++j) {
        const int pix = bm * 128 + wm * 64 + im * 16 + rsub * 4 + j;
        #pragma unroll
        for (int in = 0; in < 4; ++in) {
          const int f = bn * 128 + wn * 64 + in * 16 + l16;
          out[pix * 256 + f] = fmaxf(acc[im][in][j] + bval[in], 0.f);
        }
      }
    }
  }
}

// per-channel stats + fold-minmax contribution: one block per channel
__global__ __launch_bounds__(256)
void kstats(const float* __restrict__ psum, const float* __restrict__ psq,
            const float* __restrict__ gamma, const float* __restrict__ beta,
            float* __restrict__ scale, float* __restrict__ bias,
            const float* __restrict__ wfmin, const float* __restrict__ wfmax,
            unsigned* __restrict__ enc)
{
  const int ch = blockIdx.x;
  const int bn = ch >> 7, col = ch & 127;
  float s = 0.f, q = 0.f;
  for (int bm = threadIdx.x; bm < MT128; bm += 256) {
    s += psum[(bm * 2 + bn) * 128 + col];
    q += psq[(bm * 2 + bn) * 128 + col];
  }
  #pragma unroll
  for (int off = 32; off > 0; off >>= 1) {
    s += __shfl_xor(s, off);
    q += __shfl_xor(q, off);
  }
  __shared__ float ss[4], sq2[4];
  const int lane = threadIdx.x & 63, w = threadIdx.x >> 6;
  if (lane == 0) { ss[w] = s; sq2[w] = q; }
  __syncthreads();
  if (threadIdx.x == 0) {
    s = ss[0] + ss[1] + ss[2] + ss[3];
    q = sq2[0] + sq2[1] + sq2[2] + sq2[3];
    const float inv = 1.0f / (float)NPIX;
    const float mean = s * inv;
    const float var = q * inv - mean * mean;
    const float istd = 1.0f / sqrtf(var + 1e-5f);
    const float g = gamma[ch];
    const float sc = g * istd;
    scale[ch] = sc;
    bias[ch] = beta[ch] - g * mean * istd;
    const float p0 = sc * wfmin[ch];
    const float p1 = sc * wfmax[ch];
    atomicMin(&enc[2], encf(fminf(p0, p1)));
    atomicMax(&enc[3], encf(fmaxf(p0, p1)));
  }
}

extern "C" void kernel_launch(void* const* d_in, const int* in_sizes, int n_in,
                              void* d_out, int out_size, void* d_ws, size_t ws_size,
                              hipStream_t stream)
{
  const float* x     = (const float*)d_in[0];
  const float* W     = (const float*)d_in[1];
  const float* gamma = (const float*)d_in[2];
  const float* beta  = (const float*)d_in[3];
  float* out = (float*)d_out;
  char* ws = (char*)d_ws;

  unsigned* enc        = (unsigned*)(ws + OFF_ENC);
  float* scale         = (float*)(ws + OFF_SCALE);
  float* bias          = (float*)(ws + OFF_BIAS);
  unsigned short* Wt   = (unsigned short*)(ws + OFF_WT);
  unsigned short* Wqt  = (unsigned short*)(ws + OFF_WQT);
  float* psum          = (float*)(ws + OFF_PSUM);
  float* wfmin         = (float*)(ws + OFF_WFMIN);
  float* wfmax         = (float*)(ws + OFF_WFMAX);
  float* psq           = (float*)(ws + OFF_PSQ);
  unsigned short* xpad  = (unsigned short*)(ws + OFF_XPAD);
  unsigned short* xqpad = (unsigned short*)(ws + OFF_XQPAD);

  kinit<<<1, 64, 0, stream>>>(enc);
  kminmax<<<1024, 256, 0, stream>>>((const float4*)x, enc);
  kpadfill<<<8136, 256, 0, stream>>>(x, enc, xpad, xqpad, W, Wt, wfmin, wfmax);
  kconv<1><<<1568, 256, 0, stream>>>(xpad, Wt, nullptr, nullptr, psum, psq);
  kstats<<<256, 256, 0, stream>>>(psum, psq, gamma, beta, scale, bias, wfmin, wfmax, enc);
  kwq<<<1152, 256, 0, stream>>>(W, scale, enc, Wqt);
  kconv<0><<<1568, 256, 0, stream>>>(xqpad, Wqt, out, bias, nullptr, nullptr);
}

// Round 15
// 214.858 us; speedup vs baseline: 1.5527x; 1.5527x over previous
//
#include <hip/hip_runtime.h>

typedef float f32x4_t __attribute__((ext_vector_type(4)));
typedef __bf16 bf16x8_t __attribute__((ext_vector_type(8)));
typedef unsigned short u16x8_t __attribute__((ext_vector_type(8)));

// ---- geometry ----
#define NPIX        100352      // 32*56*56
#define PIX_PER_IMG 3136        // 56*56
#define PH          58
#define PPIX        3364        // 58*58
#define C_IN        128
#define C_OUT       256
#define NV4         3211264     // x as float4 count
#define NWELEM      294912      // 3*3*128*256
#define MTILES      392         // NPIX/256
#define NPADPIX     107648      // 32*58*58

// ---- ws byte offsets ----
#define OFF_ENC     0           // 4 x u32 (x min/max, wfold min/max encodings)
#define OFF_SCALE   64          // 256 f32
#define OFF_BIAS    1152        // 256 f32
#define OFF_WT      4096        // 589824 B bf16 [9][256 f][128 c]
#define OFF_WQT     593920      // 589824 B
#define OFF_PSUM    1183744     // 784*128 f32 = 401408 B used
#define OFF_WFMIN   1585152     // 256 f32 (spare upper half of PSUM region)
#define OFF_WFMAX   1586176     // 256 f32
#define OFF_PSQ     1986560     // 784*128 f32
#define OFF_XPAD    2789376     // 27557888 B bf16 [32][58][58][128]
#define OFF_XQPAD   30347264    // 27557888 B   (end: 57905152)

// ---- helpers ----
__device__ __forceinline__ unsigned short f2bf(float x) {
  unsigned u = __float_as_uint(x);
  u += 0x7FFFu + ((u >> 16) & 1u);   // RNE
  return (unsigned short)(u >> 16);
}
__device__ __forceinline__ unsigned encf(float v) {
  unsigned u = __float_as_uint(v);
  return (u & 0x80000000u) ? ~u : (u | 0x80000000u);
}
__device__ __forceinline__ float decf(unsigned e) {
  unsigned u = (e & 0x80000000u) ? (e ^ 0x80000000u) : ~e;
  return __uint_as_float(u);
}
__device__ __forceinline__ void gl_lds16(const void* g, void* l) {
  auto gp = (const __attribute__((address_space(1))) unsigned*)(const unsigned*)g;
  auto lp = (__attribute__((address_space(3))) unsigned*)(unsigned*)l;
  __builtin_amdgcn_global_load_lds(gp, lp, 16, 0, 0);
}
#define SCHED_FENCE() __builtin_amdgcn_sched_barrier(0)

// ---- kernels ----
__global__ void kinit(unsigned* enc) {
  enc[0] = 0xFFFFFFFFu; enc[1] = 0u;   // x min/max encodings
  enc[2] = 0xFFFFFFFFu; enc[3] = 0u;   // wfold min/max encodings
}

__global__ void kminmax(const float4* __restrict__ x, unsigned* __restrict__ enc) {
  const int tid = blockIdx.x * blockDim.x + threadIdx.x;
  const int stride = gridDim.x * blockDim.x;
  float mn = 3.4e38f, mx = -3.4e38f;
  for (int i = tid; i < NV4; i += stride) {
    float4 v = x[i];
    mn = fminf(mn, fminf(fminf(v.x, v.y), fminf(v.z, v.w)));
    mx = fmaxf(mx, fmaxf(fmaxf(v.x, v.y), fmaxf(v.z, v.w)));
  }
  #pragma unroll
  for (int off = 32; off > 0; off >>= 1) {
    mn = fminf(mn, __shfl_xor(mn, off));
    mx = fmaxf(mx, __shfl_xor(mx, off));
  }
  __shared__ float smn[4], smx[4];
  const int lane = threadIdx.x & 63, w = threadIdx.x >> 6;
  if (lane == 0) { smn[w] = mn; smx[w] = mx; }
  __syncthreads();
  if (threadIdx.x == 0) {
    mn = fminf(fminf(smn[0], smn[1]), fminf(smn[2], smn[3]));
    mx = fmaxf(fmaxf(smx[0], smx[1]), fmaxf(smx[2], smx[3]));
    atomicMin(&enc[0], encf(mn));
    atomicMax(&enc[1], encf(mx));
  }
}

// quantized folded weights: wqt [tap][256 f][128 c] bf16
__global__ void kwq(const float* __restrict__ W, const float* __restrict__ scale,
                    const unsigned* __restrict__ enc, unsigned short* __restrict__ wqt) {
  const int idx = blockIdx.x * 256 + threadIdx.x;
  if (idx >= NWELEM) return;
  const int c = idx & 127;
  const int f = (idx >> 7) & 255;
  const int tap = idx >> 15;
  const float wmn = decf(enc[2]), wmx = decf(enc[3]);
  const float wstep = (wmx - wmn) / 255.0f;
  const float wrstep = 255.0f / (wmx - wmn);
  const float v = W[(tap * 128 + c) * 256 + f] * scale[f];
  const float q = rintf((v - wmn) * wrstep) * wstep + wmn;
  wqt[idx] = f2bf(q);
}

// fused prep kernel, 3 regions:
//  [0, 6728):      pad-fill x -> xpad bf16 + xqpad bf16 (quantized), zero border
//  [6728, 7880):   W -> Wt [tap][256 f][128 c] bf16
//  [7880, 8136):   per-f min/max of W (stats-independent) -> wfmin/wfmax[256]
__global__ void kpadfill(const float* __restrict__ x, const unsigned* __restrict__ enc,
                         unsigned short* __restrict__ xpad, unsigned short* __restrict__ xqpad,
                         const float* __restrict__ W, unsigned short* __restrict__ wtt,
                         float* __restrict__ wfmin, float* __restrict__ wfmax)
{
  if (blockIdx.x >= 7880) {
    // per-f W min/max: one block per output channel f
    const int f = blockIdx.x - 7880;
    float mn = 3.4e38f, mx = -3.4e38f;
    for (int e = threadIdx.x; e < 1152; e += 256) {
      const float v = W[e * 256 + f];
      mn = fminf(mn, v); mx = fmaxf(mx, v);
    }
    #pragma unroll
    for (int off = 32; off > 0; off >>= 1) {
      mn = fminf(mn, __shfl_xor(mn, off));
      mx = fmaxf(mx, __shfl_xor(mx, off));
    }
    __shared__ float rmn[4], rmx[4];
    const int lane = threadIdx.x & 63, w = threadIdx.x >> 6;
    if (lane == 0) { rmn[w] = mn; rmx[w] = mx; }
    __syncthreads();
    if (threadIdx.x == 0) {
      wfmin[f] = fminf(fminf(rmn[0], rmn[1]), fminf(rmn[2], rmn[3]));
      wfmax[f] = fmaxf(fmaxf(rmx[0], rmx[1]), fmaxf(rmx[2], rmx[3]));
    }
    return;
  }
  if (blockIdx.x >= 6728) {
    const int idx = (blockIdx.x - 6728) * 256 + threadIdx.x;
    if (idx < NWELEM) {
      const int c = idx & 127;
      const int f = (idx >> 7) & 255;
      const int tap = idx >> 15;
      wtt[idx] = f2bf(W[(tap * 128 + c) * 256 + f]);
    }
    return;
  }
  const int tid = blockIdx.x * 256 + threadIdx.x;
  if (tid >= NPADPIX * 16) return;
  const int pp = tid >> 4;
  const int c8 = (tid & 15) << 3;
  const int n = pp / PPIX;
  const int rem = pp - n * PPIX;
  const int hp = rem / PH;
  const int wp = rem - hp * PH;
  u16x8_t vb, vq;
  #pragma unroll
  for (int j = 0; j < 8; ++j) { vb[j] = 0; vq[j] = 0; }
  if (hp >= 1 && hp <= 56 && wp >= 1 && wp <= 56) {
    const float mn = decf(enc[0]), mx = decf(enc[1]);
    const float step = (mx - mn) / 255.0f, rstep = 255.0f / (mx - mn);
    const float* src = x + ((n * PIX_PER_IMG) + (hp - 1) * 56 + (wp - 1)) * C_IN + c8;
    const float4 a = *(const float4*)src;
    const float4 b = *(const float4*)(src + 4);
    const float v[8] = {a.x, a.y, a.z, a.w, b.x, b.y, b.z, b.w};
    #pragma unroll
    for (int j = 0; j < 8; ++j) {
      vb[j] = f2bf(v[j]);
      const float qv = rintf((v[j] - mn) * rstep) * step + mn;
      vq[j] = f2bf(qv);
    }
  }
  *(u16x8_t*)(xpad + pp * C_IN + c8) = vb;
  *(u16x8_t*)(xqpad + pp * C_IN + c8) = vq;
}

// implicit-GEMM conv (R8/R12-proven best). BM=256, BN=128 (bn = N-half), BK=32.
// 512 threads, 8 waves 4(M)x2(N), wave tile 64x64, acc 4x4 f32x4 (64 regs).
// LDS 48KB: 2 buffers x [A 16KB][B 8KB]. A stored as [128 rows][128B] where row r
// holds pixels {r, r+128} (64B each); logical chunk lc = half*4 + rsub, phys =
// lc ^ (row&7) (both-sides XOR swizzle, rule #21). 36 K-tiles, counted vmcnt(3).
// 2 blocks/CU -> cross-block latency hiding (m114).
// STATS=1: per-block column sum/sumsq partials. STATS=0: out = relu(conv + bias).
template<int STATS>
__global__ __launch_bounds__(512, 4)
void kconv(const unsigned short* __restrict__ xin,   // padded bf16 [32][58][58][128]
           const unsigned short* __restrict__ wt,    // bf16 [9][256 f][128 c]
           float* __restrict__ out,
           const float* __restrict__ bias,
           float* __restrict__ psum,
           float* __restrict__ psq)
{
  // XCD-aware bijective swizzle: 784 = 8*98; (bm,0)/(bm,1) adjacent on same XCD.
  const int bid = blockIdx.x;
  const int slot = (bid & 7) * 98 + (bid >> 3);   // 0..783
  const int bm = slot >> 1;                        // 0..391
  const int bn = slot & 1;                         // N-half

  const int tid = threadIdx.x;
  const int lane = tid & 63;
  const int wid = tid >> 6;
  const int wm = wid >> 1;          // 0..3
  const int wn = wid & 1;           // 0..1
  const int l16 = lane & 15;
  const int rsub = lane >> 4;

  __shared__ __align__(16) unsigned char smem[49152];   // 2 x (A 16KB + B 8KB)

  // ---- staging offsets (global source pre-swizzled; LDS dest linear) ----
  unsigned aoff[2];
  {
    const int arow0 = wid * 8 + (lane >> 3);
    const int pc = lane & 7;
    #pragma unroll
    for (int j = 0; j < 2; ++j) {
      const int row = j * 64 + arow0;
      const int lc = pc ^ (row & 7);
      const int pix = bm * 256 + row + 128 * (lc >> 2);
      const int n = pix / PIX_PER_IMG;
      const int rem = pix - n * PIX_PER_IMG;
      const int hh = rem / 56;
      const int ww = rem - hh * 56;
      aoff[j] = (unsigned)((n * PPIX + hh * PH + ww) * C_IN + (lc & 3) * 8);
    }
  }
  unsigned boff;
  {
    const int row = wid * 8 + (lane >> 3);
    const int pc = lane & 7;
    const int lc = pc ^ (row & 7);
    const int f = bn * 128 + row + 64 * (lc >> 2);
    boff = (unsigned)(f * C_IN + (lc & 3) * 8);
  }

  // ---- ds_read byte offsets (within a buffer) ----
  int a_rd[4], b_rd[4];
  #pragma unroll
  for (int im = 0; im < 4; ++im) {
    const int p = wm * 64 + im * 16 + l16;          // pixel index in tile, 0..255
    const int row = p & 127, half = p >> 7;
    const int phys = (half * 4 + rsub) ^ (row & 7);
    a_rd[im] = row * 128 + phys * 16;
  }
  #pragma unroll
  for (int in = 0; in < 4; ++in) {
    const int f = wn * 64 + in * 16 + l16;          // f index in tile, 0..127
    const int row = f & 63, half = f >> 6;
    const int phys = (half * 4 + rsub) ^ (row & 7);
    b_rd[in] = row * 128 + phys * 16;
  }

  f32x4_t acc[4][4];
  #pragma unroll
  for (int im = 0; im < 4; ++im)
    #pragma unroll
    for (int in = 0; in < 4; ++in)
      #pragma unroll
      for (int j = 0; j < 4; ++j) acc[im][in][j] = 0.f;

  // stage tile s into buffer (s&1): 3 loads/thread
  auto stage = [&](int s) {
    const int tap = s >> 2;
    const int cq = (s & 3) * 32;
    const int kh = tap / 3, kw = tap - kh * 3;
    const unsigned atap = (unsigned)((kh * PH + kw) * C_IN + cq);
    const unsigned btap = (unsigned)(tap * (C_OUT * C_IN) + cq);
    unsigned char* sA = smem + (s & 1) * 24576;
    unsigned char* sB = sA + 16384;
    gl_lds16(xin + atap + aoff[0], sA + wid * 1024);
    gl_lds16(xin + atap + aoff[1], sA + 8192 + wid * 1024);
    gl_lds16(wt + btap + boff, sB + wid * 1024);
  };

  auto compute = [&](int s) {
    const unsigned char* sA = smem + (s & 1) * 24576;
    const unsigned char* sB = sA + 16384;
    bf16x8_t av[4], bv[4];
    #pragma unroll
    for (int im = 0; im < 4; ++im) av[im] = *(const bf16x8_t*)(sA + a_rd[im]);
    #pragma unroll
    for (int in = 0; in < 4; ++in) bv[in] = *(const bf16x8_t*)(sB + b_rd[in]);
    #pragma unroll
    for (int im = 0; im < 4; ++im)
      #pragma unroll
      for (int in = 0; in < 4; ++in)
        acc[im][in] = __builtin_amdgcn_mfma_f32_16x16x32_bf16(av[im], bv[in], acc[im][in], 0, 0, 0);
  };

  stage(0);
  stage(1);

  // 36 K-tiles (9 taps x 4 channel-quarters); last iter peeled for vmcnt(0)
  #pragma unroll 1
  for (int s = 0; s < 35; ++s) {
    asm volatile("s_waitcnt vmcnt(3)" ::: "memory");   // tile s landed; s+1 in flight
    SCHED_FENCE();
    __builtin_amdgcn_s_barrier();
    SCHED_FENCE();
    compute(s);
    SCHED_FENCE();
    __builtin_amdgcn_s_barrier();   // all waves done reading buf[s&1]
    SCHED_FENCE();
    if (s < 34) stage(s + 2);       // refill just-freed buffer
  }
  asm volatile("s_waitcnt vmcnt(0)" ::: "memory");
  SCHED_FENCE();
  __builtin_amdgcn_s_barrier();
  SCHED_FENCE();
  compute(35);

  if (STATS) {
    __syncthreads();
    float* sb = (float*)smem;      // [8 waves][64 cols] sums; sumsq at +512
    #pragma unroll
    for (int in = 0; in < 4; ++in) {
      float s = 0.f, q = 0.f;
      #pragma unroll
      for (int im = 0; im < 4; ++im)
        #pragma unroll
        for (int j = 0; j < 4; ++j) {
          const float v = acc[im][in][j];
          s += v; q += v * v;
        }
      s += __shfl_xor(s, 16); q += __shfl_xor(q, 16);
      s += __shfl_xor(s, 32); q += __shfl_xor(q, 32);
      if (lane < 16) {
        sb[wid * 64 + in * 16 + lane] = s;
        sb[512 + wid * 64 + in * 16 + lane] = q;
      }
    }
    __syncthreads();
    if (tid < 128) {
      const int wn2 = tid >> 6, cl = tid & 63;   // channel c = wn2*64 + cl
      float s = 0.f, q = 0.f;
      #pragma unroll
      for (int wm2 = 0; wm2 < 4; ++wm2) {
        s += sb[(wm2 * 2 + wn2) * 64 + cl];
        q += sb[512 + (wm2 * 2 + wn2) * 64 + cl];
      }
      psum[(bm * 2 + bn) * 128 + tid] = s;
      psq[(bm * 2 + bn) * 128 + tid] = q;
    }
  } else {
    float bval[4];
    #pragma unroll
    for (int in = 0; in < 4; ++in)
      bval[in] = bias[bn * 128 + wn * 64 + in * 16 + l16];
    #pragma unroll
    for (int im = 0; im < 4; ++im) {
      #pragma unroll
      for (int j = 0; j < 4; ++j) {
        const int pix = bm * 256 + wm * 64 + im * 16 + rsub * 4 + j;
        #pragma unroll
        for (int in = 0; in < 4; ++in) {
          const int f = bn * 128 + wn * 64 + in * 16 + l16;
          out[pix * 256 + f] = fmaxf(acc[im][in][j] + bval[in], 0.f);
        }
      }
    }
  }
}

// per-channel stats + fold-minmax contribution: one block per channel
__global__ __launch_bounds__(256)
void kstats(const float* __restrict__ psum, const float* __restrict__ psq,
            const float* __restrict__ gamma, const float* __restrict__ beta,
            float* __restrict__ scale, float* __restrict__ bias,
            const float* __restrict__ wfmin, const float* __restrict__ wfmax,
            unsigned* __restrict__ enc)
{
  const int ch = blockIdx.x;
  const int bn = ch >> 7, col = ch & 127;
  float s = 0.f, q = 0.f;
  for (int bm = threadIdx.x; bm < MTILES; bm += 256) {
    s += psum[(bm * 2 + bn) * 128 + col];
    q += psq[(bm * 2 + bn) * 128 + col];
  }
  #pragma unroll
  for (int off = 32; off > 0; off >>= 1) {
    s += __shfl_xor(s, off);
    q += __shfl_xor(q, off);
  }
  __shared__ float ss[4], sq2[4];
  const int lane = threadIdx.x & 63, w = threadIdx.x >> 6;
  if (lane == 0) { ss[w] = s; sq2[w] = q; }
  __syncthreads();
  if (threadIdx.x == 0) {
    s = ss[0] + ss[1] + ss[2] + ss[3];
    q = sq2[0] + sq2[1] + sq2[2] + sq2[3];
    const float inv = 1.0f / (float)NPIX;
    const float mean = s * inv;
    const float var = q * inv - mean * mean;
    const float istd = 1.0f / sqrtf(var + 1e-5f);
    const float g = gamma[ch];
    const float sc = g * istd;
    scale[ch] = sc;
    bias[ch] = beta[ch] - g * mean * istd;
    // fold min/max for this channel: min/max over c of sc*W[:,c,ch] — exact via
    // per-f extremes (same FP multiply as the elementwise scan; sign-aware).
    const float p0 = sc * wfmin[ch];
    const float p1 = sc * wfmax[ch];
    atomicMin(&enc[2], encf(fminf(p0, p1)));
    atomicMax(&enc[3], encf(fmaxf(p0, p1)));
  }
}

extern "C" void kernel_launch(void* const* d_in, const int* in_sizes, int n_in,
                              void* d_out, int out_size, void* d_ws, size_t ws_size,
                              hipStream_t stream)
{
  const float* x     = (const float*)d_in[0];
  const float* W     = (const float*)d_in[1];
  const float* gamma = (const float*)d_in[2];
  const float* beta  = (const float*)d_in[3];
  float* out = (float*)d_out;
  char* ws = (char*)d_ws;

  unsigned* enc        = (unsigned*)(ws + OFF_ENC);
  float* scale         = (float*)(ws + OFF_SCALE);
  float* bias          = (float*)(ws + OFF_BIAS);
  unsigned short* Wt   = (unsigned short*)(ws + OFF_WT);
  unsigned short* Wqt  = (unsigned short*)(ws + OFF_WQT);
  float* psum          = (float*)(ws + OFF_PSUM);
  float* wfmin         = (float*)(ws + OFF_WFMIN);
  float* wfmax         = (float*)(ws + OFF_WFMAX);
  float* psq           = (float*)(ws + OFF_PSQ);
  unsigned short* xpad  = (unsigned short*)(ws + OFF_XPAD);
  unsigned short* xqpad = (unsigned short*)(ws + OFF_XQPAD);

  kinit<<<1, 64, 0, stream>>>(enc);
  kminmax<<<1024, 256, 0, stream>>>((const float4*)x, enc);
  kpadfill<<<8136, 256, 0, stream>>>(x, enc, xpad, xqpad, W, Wt, wfmin, wfmax);
  kconv<1><<<784, 512, 0, stream>>>(xpad, Wt, nullptr, nullptr, psum, psq);
  kstats<<<256, 256, 0, stream>>>(psum, psq, gamma, beta, scale, bias, wfmin, wfmax, enc);
  kwq<<<1152, 256, 0, stream>>>(W, scale, enc, Wqt);
  kconv<0><<<784, 512, 0, stream>>>(xqpad, Wqt, out, bias, nullptr, nullptr);
}